// Round 3
// baseline (107.896 us; speedup 1.0000x reference)
//
#include <hip/hip_runtime.h>

// Problem constants (fixed by setup_inputs)
#define T_DIM 32
#define B_DIM 64
#define D_DIM 256
#define P_DIM 1024
#define NK    17
#define DT    0.1875f   // 3/16

// ---------------------------------------------------------------------------
// Main kernel: fused column-norm + x = proj@A*inv + cos/sin B-sums + weighted
// error -> one partial per block.
// grid (16 ptile, 32 t) x 512 threads (8 waves; wave w handles b in [8w,8w+8)).
// Key change vs round 2: proj (the wave-uniform operand) is read from GLOBAL
// with wave-uniform addresses (readfirstlane -> s_load), ping-pong double
// buffered in registers. Only A goes through LDS (4x ds_read_b32 per 4-d
// group = 23 LDS-cyc vs 72 VALU-cyc -> VALU-bound).
// LDS 64 KB: phase A = A tile [256][64]; reused for the reduction planes.
// ---------------------------------------------------------------------------
__global__ __launch_bounds__(512, 4) void sig_main_kernel(const float* __restrict__ proj,
                                                          const float* __restrict__ A,
                                                          float* __restrict__ partials) {
  __shared__ float smem[16384];          // 64 KB
  const int tid  = threadIdx.x;
  const int lane = tid & 63;
  const int p0   = blockIdx.x * 64;
  const int t    = blockIdx.y;
  // force wave index to be compiler-visibly uniform -> scalar proj loads
  const int wv   = __builtin_amdgcn_readfirstlane(tid >> 6);   // 0..7

  // ---- stage A tile: smem[d*64 + pl] = A[d][p0+pl] ----
  {
    const float4* Ag = (const float4*)(A + p0);   // row stride 256 float4
    float4* s4 = (float4*)smem;
#pragma unroll
    for (int r = 0; r < 8; ++r) {
      int i = tid + r * 512;             // i in [0,4096)
      int d = i >> 4, c = i & 15;
      s4[i] = Ag[d * (P_DIM / 4) + c];
    }
  }
  __syncthreads();

  // ---- phase A: xacc[j] = sum_d proj[t][b0+j][d] * A[d][p0+lane] ----
  // proj base for this wave's 8 b-rows; group g = float4 index (4 d's)
  const float4* Pg = (const float4*)(proj + ((size_t)(t * B_DIM + wv * 8)) * D_DIM);

  float xacc[8];
#pragma unroll
  for (int j = 0; j < 8; ++j) xacc[j] = 0.f;
  float nacc = 0.f;                      // sum_d A[d][p]^2

  float4 pa[8], pb[8];                   // ping-pong uniform proj buffers
#pragma unroll
  for (int j = 0; j < 8; ++j) pa[j] = Pg[j * 64 + 0];
#pragma unroll
  for (int j = 0; j < 8; ++j) pb[j] = Pg[j * 64 + 1];

  for (int g = 0; g < 64; g += 2) {
    // ---- group g (buffer pa), then prefetch pa <- g+2 ----
    {
      int dd = 4 * g;
      float a0 = smem[(dd + 0) * 64 + lane];   // 2-way bank alias: free
      float a1 = smem[(dd + 1) * 64 + lane];
      float a2 = smem[(dd + 2) * 64 + lane];
      float a3 = smem[(dd + 3) * 64 + lane];
      nacc = fmaf(a0, a0, nacc);
      nacc = fmaf(a1, a1, nacc);
      nacc = fmaf(a2, a2, nacc);
      nacc = fmaf(a3, a3, nacc);
#pragma unroll
      for (int j = 0; j < 8; ++j) {
        xacc[j] = fmaf(pa[j].x, a0, xacc[j]);
        xacc[j] = fmaf(pa[j].y, a1, xacc[j]);
        xacc[j] = fmaf(pa[j].z, a2, xacc[j]);
        xacc[j] = fmaf(pa[j].w, a3, xacc[j]);
      }
    }
    {
      int gp = (g + 2 < 64) ? (g + 2) : 63;    // clamped tail prefetch (no OOB)
#pragma unroll
      for (int j = 0; j < 8; ++j) pa[j] = Pg[j * 64 + gp];
    }
    // ---- group g+1 (buffer pb), then prefetch pb <- g+3 ----
    {
      int dd = 4 * g + 4;
      float a0 = smem[(dd + 0) * 64 + lane];
      float a1 = smem[(dd + 1) * 64 + lane];
      float a2 = smem[(dd + 2) * 64 + lane];
      float a3 = smem[(dd + 3) * 64 + lane];
      nacc = fmaf(a0, a0, nacc);
      nacc = fmaf(a1, a1, nacc);
      nacc = fmaf(a2, a2, nacc);
      nacc = fmaf(a3, a3, nacc);
#pragma unroll
      for (int j = 0; j < 8; ++j) {
        xacc[j] = fmaf(pb[j].x, a0, xacc[j]);
        xacc[j] = fmaf(pb[j].y, a1, xacc[j]);
        xacc[j] = fmaf(pb[j].z, a2, xacc[j]);
        xacc[j] = fmaf(pb[j].w, a3, xacc[j]);
      }
    }
    {
      int gp = (g + 3 < 64) ? (g + 3) : 63;
#pragma unroll
      for (int j = 0; j < 8; ++j) pb[j] = Pg[j * 64 + gp];
    }
  }

  // ---- phase B: trig via Chebyshev recurrence over this lane's 8 b's ----
  const float inv = rsqrtf(fmaxf(nacc, 1e-24f));   // 1/clamp_min(norm,1e-12)
  float cs[NK], ss[NK];
#pragma unroll
  for (int k = 1; k < NK; ++k) { cs[k] = 0.f; ss[k] = 0.f; }

#pragma unroll
  for (int j = 0; j < 8; ++j) {
    float th = xacc[j] * inv * DT;
    float s1, c1;
    __sincosf(th, &s1, &c1);
    float twoc = 2.f * c1;
    float ckm1 = 1.f, skm1 = 0.f;        // k=0
    float ck = c1, sk = s1;              // k=1
    cs[1] += c1;
    ss[1] += s1;
#pragma unroll
    for (int k = 2; k < NK; ++k) {
      float cn = fmaf(twoc, ck, -ckm1);
      float sn = fmaf(twoc, sk, -skm1);
      cs[k] += cn;
      ss[k] += sn;
      ckm1 = ck; skm1 = sk; ck = cn; sk = sn;
    }
  }

  // ---- write wave-partial cos/sin sums (k=1..16; k=0 err is exactly 0) ----
  __syncthreads();                       // all waves done reading A tile
#pragma unroll
  for (int k = 1; k < NK; ++k) {
    int k1 = k - 1;
    smem[k1 * 512 + wv * 64 + lane]        = cs[k];   // cos planes [16][8][64]
    smem[8192 + k1 * 512 + wv * 64 + lane] = ss[k];   // sin planes
  }
  __syncthreads();

  // ---- per-(k,p) error + weight dot; 1024 entries over 512 threads ----
  float part = 0.f;
#pragma unroll
  for (int r = 0; r < 2; ++r) {
    int e  = tid + r * 512;              // e in [0, 16*64)
    int k1 = e >> 6;
    int pl = e & 63;
    const float* bc = &smem[k1 * 512 + pl];
    const float* bs = &smem[8192 + k1 * 512 + pl];
    float C = 0.f, S = 0.f;
#pragma unroll
    for (int w = 0; w < 8; ++w) { C += bc[w * 64]; S += bs[w * 64]; }
    float cm  = C * (1.f / 64.f);
    float sm  = S * (1.f / 64.f);
    float tk  = (float)(k1 + 1) * DT;
    float phi = __expf(-0.5f * tk * tk);
    float wk  = ((k1 == NK - 2) ? DT : 2.f * DT) * phi;  // k=16 endpoint weight
    float dc  = cm - phi;
    part = fmaf(wk, fmaf(dc, dc, sm * sm), part);
  }
  part *= (1.f / 512.f);                 // * B / (T*P)

  // ---- block reduce ----
#pragma unroll
  for (int off = 32; off > 0; off >>= 1)
    part += __shfl_down(part, off, 64);
  __syncthreads();                       // done reading planes
  if (lane == 0) smem[wv] = part;
  __syncthreads();
  if (tid == 0) {
    float s = 0.f;
#pragma unroll
    for (int w = 0; w < 8; ++w) s += smem[w];
    partials[blockIdx.y * 16 + blockIdx.x] = s;
  }
}

// ---------------------------------------------------------------------------
// Finalize: sum 512 block partials -> scalar
// ---------------------------------------------------------------------------
__global__ __launch_bounds__(256) void sig_finalize_kernel(const float* __restrict__ partials,
                                                           float* __restrict__ out) {
  __shared__ float red[4];
  const int tid  = threadIdx.x;
  const int lane = tid & 63;
  const int wave = tid >> 6;
  float v = partials[tid] + partials[tid + 256];
#pragma unroll
  for (int off = 32; off > 0; off >>= 1)
    v += __shfl_down(v, off, 64);
  if (lane == 0) red[wave] = v;
  __syncthreads();
  if (tid == 0) out[0] = red[0] + red[1] + red[2] + red[3];
}

// ---------------------------------------------------------------------------
extern "C" void kernel_launch(void* const* d_in, const int* in_sizes, int n_in,
                              void* d_out, int out_size, void* d_ws, size_t ws_size,
                              hipStream_t stream) {
  const float* proj = (const float*)d_in[0];   // (32,64,256) fp32
  const float* A    = (const float*)d_in[1];   // (256,1024) fp32
  float* partials   = (float*)d_ws;            // 512 floats scratch
  float* out        = (float*)d_out;           // 1 fp32 scalar

  sig_main_kernel<<<dim3(16, 32), dim3(512), 0, stream>>>(proj, A, partials);
  sig_finalize_kernel<<<dim3(1), dim3(256), 0, stream>>>(partials, out);
}

// Round 5
// 72.259 us; speedup vs baseline: 1.4932x; 1.4932x over previous
//
#include <hip/hip_runtime.h>

// Problem constants (fixed by setup_inputs)
#define T_DIM 32
#define B_DIM 64
#define D_DIM 256
#define P_DIM 1024
#define NK    17
#define DT    0.1875f    // 3/16

#define KC    128        // K-chunk for the MFMA tiles
#define LROW  136        // padded LDS row (128 + 8 bf16): 272 B, 16B-aligned
#define PROW  264        // prep kernel's A-tile row (256 + 8 bf16)

typedef __bf16 bf16x8 __attribute__((ext_vector_type(8)));
typedef float  f32x16 __attribute__((ext_vector_type(16)));

static __device__ __forceinline__ unsigned short f2bf(float f) {
  unsigned u = __float_as_uint(f);
  u += 0x7fffu + ((u >> 16) & 1u);     // round-to-nearest-even
  return (unsigned short)(u >> 16);
}

// ---------------------------------------------------------------------------
// K1 prep: blocks 0..15  -> ATbf[p][d] = bf16(A[d][p] / clamp(norm_p)) (transposed)
//          blocks 16..79 -> projbf = bf16(proj) (elementwise, 2048 float4/block)
// ---------------------------------------------------------------------------
__global__ __launch_bounds__(256) void prep_kernel(const float* __restrict__ proj,
                                                   const float* __restrict__ A,
                                                   unsigned short* __restrict__ projbf,
                                                   unsigned short* __restrict__ ATbf) {
  const int tid = threadIdx.x;
  if (blockIdx.x < 16) {
    __shared__ unsigned short tile[64 * PROW];   // [p][d], padded
    __shared__ float red[4][64];
    __shared__ float invn[64];
    const int pl = tid & 63;
    const int dq = tid >> 6;                     // 0..3
    const int p0 = blockIdx.x * 64;
    const float* Ac = A + p0 + pl;
    float s = 0.f;
#pragma unroll 8
    for (int i = 0; i < 64; ++i) {
      float v = Ac[(size_t)(dq * 64 + i) * P_DIM];   // coalesced over pl
      s = fmaf(v, v, s);
    }
    red[dq][pl] = s;
    __syncthreads();
    if (tid < 64) {
      float tot = red[0][pl] + red[1][pl] + red[2][pl] + red[3][pl];
      invn[pl] = rsqrtf(fmaxf(tot, 1e-24f));     // 1/clamp_min(norm,1e-12)
    }
    __syncthreads();
    const float inv = invn[pl];
#pragma unroll 8
    for (int i = 0; i < 64; ++i) {
      int d = dq * 64 + i;
      float v = Ac[(size_t)d * P_DIM] * inv;     // L2-warm re-read
      tile[pl * PROW + d] = f2bf(v);
    }
    __syncthreads();
    // cooperative coalesced store: 64 rows x 256 bf16 (strip the pad)
#pragma unroll
    for (int r = 0; r < 8; ++r) {
      int idx = tid + r * 256;                   // 0..2047 uint4 units
      int row = idx >> 5, c = idx & 31;
      uint4 v = *(const uint4*)&tile[row * PROW + c * 8];
      *(uint4*)(ATbf + ((size_t)(p0 + row) * D_DIM + c * 8)) = v;
    }
  } else {
    // proj cast: 64 blocks x 2048 float4 each (proj = 131072 float4 total)
    const int pb = blockIdx.x - 16;
    const float4* src = (const float4*)proj + (size_t)pb * 2048;
    unsigned short* dst = projbf + (size_t)pb * 8192;
#pragma unroll
    for (int r = 0; r < 8; ++r) {
      int i = tid + r * 256;                     // 0..2047
      float4 v = src[i];
      ushort4 o;
      o.x = f2bf(v.x); o.y = f2bf(v.y); o.z = f2bf(v.z); o.w = f2bf(v.w);
      *(ushort4*)(dst + (size_t)i * 4) = o;
    }
  }
}

// ---------------------------------------------------------------------------
// K2 main: grid (16 ptile, 32 t) x 256 thr (4 waves).
// X = projbf @ ATbf^T via 32x32x16 bf16 MFMA, K chunked 2x128 so both LDS
// tiles fit in 34816 B. Wave wv owns tile (mt=wv>>1 of b, nt=wv&1 of p).
// Then Chebyshev cos/sin sums over B, weighted error -> partials[block].
// ---------------------------------------------------------------------------
__global__ __launch_bounds__(256) void sig_main_kernel(const unsigned short* __restrict__ projbf,
                                                       const unsigned short* __restrict__ ATbf,
                                                       float* __restrict__ partials) {
  __shared__ unsigned short sm[2 * 64 * LROW];   // 34816 B
  float* smf = (float*)sm;                       // reduction-plane alias (16.4 KB used)
  const int tid  = threadIdx.x;
  const int lane = tid & 63;
  const int wv   = tid >> 6;                     // 0..3
  const int p0   = blockIdx.x * 64;
  const int t    = blockIdx.y;

  unsigned short* sp = sm;                       // proj chunk [b][k] (padded)
  unsigned short* sa = sm + 64 * LROW;           // A^T chunk  [p][k] (padded)

  const unsigned short* gp = projbf + (size_t)t * B_DIM * D_DIM;
  const unsigned short* ga = ATbf + (size_t)p0 * D_DIM;

  const int mt = wv >> 1, nt = wv & 1;
  const int mrow = mt * 32 + (lane & 31);        // b row
  const int nrow = nt * 32 + (lane & 31);        // p row
  const int koff = (lane >> 5) * 8;

  f32x16 acc = {0.f, 0.f, 0.f, 0.f, 0.f, 0.f, 0.f, 0.f,
                0.f, 0.f, 0.f, 0.f, 0.f, 0.f, 0.f, 0.f};

  for (int kc = 0; kc < D_DIM; kc += KC) {
    // ---- stage chunk: 64 rows x 128 bf16 per tile (1024 uint4 each) ----
#pragma unroll
    for (int r = 0; r < 4; ++r) {
      int idx = tid + r * 256;                   // 0..1023
      int row = idx >> 4, c = idx & 15;
      uint4 v = *(const uint4*)(gp + (size_t)row * D_DIM + kc + c * 8);
      *(uint4*)&sp[row * LROW + c * 8] = v;
      uint4 w = *(const uint4*)(ga + (size_t)row * D_DIM + kc + c * 8);
      *(uint4*)&sa[row * LROW + c * 8] = w;
    }
    __syncthreads();

    // ---- MFMA over this chunk: 8 k-steps ----
#pragma unroll
    for (int ks = 0; ks < 8; ++ks) {
      int k = ks * 16 + koff;
      bf16x8 af = *(const bf16x8*)&sp[mrow * LROW + k];
      bf16x8 bf = *(const bf16x8*)&sa[nrow * LROW + k];
      acc = __builtin_amdgcn_mfma_f32_32x32x16_bf16(af, bf, acc, 0, 0, 0);
    }
    __syncthreads();                             // reads done before restage/reuse
  }
  // acc reg r holds x[b = mt*32 + (r&3)+8*(r>>2)+4*(lane>>5)][p = nt*32 + (lane&31)]

  // ---- Chebyshev trig: cos/sin sums over this lane's 16 b's, k = 1..16 ----
  float cs[NK - 1], ss[NK - 1];
#pragma unroll
  for (int k = 0; k < NK - 1; ++k) { cs[k] = 0.f; ss[k] = 0.f; }
#pragma unroll
  for (int r = 0; r < 16; ++r) {
    float th = acc[r] * DT;
    float s1, c1;
    __sincosf(th, &s1, &c1);
    float twoc = 2.f * c1;
    float ckm1 = 1.f, skm1 = 0.f;
    float ck = c1, sk = s1;
    cs[0] += c1;
    ss[0] += s1;
#pragma unroll
    for (int k = 2; k < NK; ++k) {
      float cn = fmaf(twoc, ck, -ckm1);
      float sn = fmaf(twoc, sk, -skm1);
      cs[k - 1] += cn;
      ss[k - 1] += sn;
      ckm1 = ck; skm1 = sk; ck = cn; sk = sn;
    }
  }

  // ---- combine the two b-halves (lane L and L^32 share the same p col) ----
#pragma unroll
  for (int k = 0; k < NK - 1; ++k) {
    cs[k] += __shfl_xor(cs[k], 32, 64);
    ss[k] += __shfl_xor(ss[k], 32, 64);
  }

  // ---- planes: cos[16][2 mt][64 p] @0, sin @2048 (LDS reuse; last barrier
  //      above already separated tile reads from these writes) ----
  if (lane < 32) {
    int p = nt * 32 + (lane & 31);
#pragma unroll
    for (int k = 0; k < NK - 1; ++k) {
      smf[k * 128 + mt * 64 + p]        = cs[k];
      smf[2048 + k * 128 + mt * 64 + p] = ss[k];
    }
  }
  __syncthreads();

  // ---- per-(k,p) error + weight dot ----
  float part = 0.f;
#pragma unroll
  for (int r = 0; r < 4; ++r) {
    int e  = tid + r * 256;                      // 0..1023
    int k1 = e >> 6;
    int pl = e & 63;
    float C = smf[k1 * 128 + pl] + smf[k1 * 128 + 64 + pl];
    float S = smf[2048 + k1 * 128 + pl] + smf[2048 + k1 * 128 + 64 + pl];
    float cm  = C * (1.f / 64.f);
    float sm_ = S * (1.f / 64.f);
    float tk  = (float)(k1 + 1) * DT;
    float phi = __expf(-0.5f * tk * tk);
    float wk  = ((k1 == NK - 2) ? DT : 2.f * DT) * phi;   // k=16 endpoint
    float dc  = cm - phi;
    part = fmaf(wk, fmaf(dc, dc, sm_ * sm_), part);
  }
  part *= (1.f / 512.f);                         // * B / (T*P)

  // ---- block reduce -> one partial per block ----
#pragma unroll
  for (int off = 32; off > 0; off >>= 1)
    part += __shfl_down(part, off, 64);
  __syncthreads();                               // done reading planes
  if (lane == 0) smf[4096 + wv] = part;
  __syncthreads();
  if (tid == 0)
    partials[blockIdx.y * 16 + blockIdx.x] = smf[4096] + smf[4097] + smf[4098] + smf[4099];
}

// ---------------------------------------------------------------------------
// Finalize: sum 512 block partials -> scalar
// ---------------------------------------------------------------------------
__global__ __launch_bounds__(256) void sig_finalize_kernel(const float* __restrict__ partials,
                                                           float* __restrict__ out) {
  __shared__ float red[4];
  const int tid  = threadIdx.x;
  const int lane = tid & 63;
  const int wave = tid >> 6;
  float v = partials[tid] + partials[tid + 256];
#pragma unroll
  for (int off = 32; off > 0; off >>= 1)
    v += __shfl_down(v, off, 64);
  if (lane == 0) red[wave] = v;
  __syncthreads();
  if (tid == 0) out[0] = red[0] + red[1] + red[2] + red[3];
}

// ---------------------------------------------------------------------------
extern "C" void kernel_launch(void* const* d_in, const int* in_sizes, int n_in,
                              void* d_out, int out_size, void* d_ws, size_t ws_size,
                              hipStream_t stream) {
  const float* proj = (const float*)d_in[0];     // (32,64,256) fp32
  const float* A    = (const float*)d_in[1];     // (256,1024) fp32
  float* out        = (float*)d_out;             // 1 fp32 scalar

  unsigned short* projbf = (unsigned short*)d_ws;                              // 512K bf16 = 1 MB
  unsigned short* ATbf   = (unsigned short*)((char*)d_ws + 1536u * 1024);      // 256K bf16
  float* partials        = (float*)((char*)d_ws + 2560u * 1024);               // 512 floats

  prep_kernel<<<dim3(80), dim3(256), 0, stream>>>(proj, A, projbf, ATbf);
  sig_main_kernel<<<dim3(16, 32), dim3(256), 0, stream>>>(projbf, ATbf, partials);
  sig_finalize_kernel<<<dim3(1), dim3(256), 0, stream>>>(partials, out);
}

// Round 6
// 70.260 us; speedup vs baseline: 1.5357x; 1.0285x over previous
//
#include <hip/hip_runtime.h>

// Problem constants (fixed by setup_inputs)
#define T_DIM 32
#define B_DIM 64
#define D_DIM 256
#define P_DIM 1024
#define NK    17
#define DT    0.1875f    // 3/16

#define KC    128        // K-chunk for the MFMA tiles
#define LROW  136        // padded LDS row (128+8 bf16) = 272 B; 68 dw stride == 4 mod 32
                         // -> every b128 LDS access is 8-phase conflict-optimal

typedef __bf16 bf16x8 __attribute__((ext_vector_type(8)));
typedef float  f32x16 __attribute__((ext_vector_type(16)));

static __device__ __forceinline__ unsigned f2bf(float f) {
  unsigned u = __float_as_uint(f);
  u += 0x7fffu + ((u >> 16) & 1u);     // round-to-nearest-even
  return u >> 16;
}

// ---------------------------------------------------------------------------
// Single fused kernel. grid (16 ptile, 32 t) x 256 thr (4 waves).
//  - stages proj (fp32->bf16) and A (fp32->bf16, transposed to [p][d]) into
//    LDS per 128-wide K chunk; A column sum-of-squares accumulated during
//    staging (norm applied to acc AFTER the GEMM -- it's linear)
//  - X = proj @ A via 32x32x16 bf16 MFMA, one 32x32 tile per wave
//  - Chebyshev cos/sin sums over B, weighted error, one atomicAdd per block
// LDS: 2 bf16 tiles [64][136] (34816 B) + normred[16][64] + invn[64]
//      = 39168 B -> 4 blocks/CU capacity (grid is 2/CU).
// ---------------------------------------------------------------------------
__global__ __launch_bounds__(256) void sig_fused_kernel(const float* __restrict__ proj,
                                                        const float* __restrict__ A,
                                                        float* __restrict__ out) {
  __shared__ float smf[9792];                    // 39168 B
  unsigned short* sp = (unsigned short*)smf;     // proj tile [b][k], padded
  unsigned short* sa = sp + 64 * LROW;           // A^T tile  [p][k], padded
  float* normred = smf + 8704;                   // [16 dg][64 p]
  float* invn    = smf + 9728;                   // [64]

  const int tid  = threadIdx.x;
  const int lane = tid & 63;
  const int wv   = tid >> 6;                     // 0..3
  const int p0   = blockIdx.x * 64;
  const int t    = blockIdx.y;

  const int mt = wv >> 1, nt = wv & 1;
  const int mrow = mt * 32 + (lane & 31);        // b row of this lane's A-frag
  const int nrow = nt * 32 + (lane & 31);        // p row of this lane's B-frag
  const int koff = (lane >> 5) * 8;

  const float4* Pg = (const float4*)(proj + (size_t)t * B_DIM * D_DIM);
  const float4* Ag = (const float4*)(A + p0);    // row stride P_DIM/4 float4

  const int pg = tid & 15;                       // p-group (4 p's)
  const int dg = tid >> 4;                       // 0..15, 8 d's each

  f32x16 acc = {0.f, 0.f, 0.f, 0.f, 0.f, 0.f, 0.f, 0.f,
                0.f, 0.f, 0.f, 0.f, 0.f, 0.f, 0.f, 0.f};
  float nrm[4] = {0.f, 0.f, 0.f, 0.f};

  for (int kc = 0; kc < D_DIM; kc += KC) {
    // ---- stage proj chunk: 4 row-pairs per thread, fp32 -> bf16 ----
#pragma unroll
    for (int r = 0; r < 4; ++r) {
      int pair = tid + r * 256;                  // 0..1023
      int row = pair >> 4, cp = pair & 15;       // 16 8-wide k-groups per row
      float4 v0 = Pg[row * 64 + kc / 4 + cp * 2];
      float4 v1 = Pg[row * 64 + kc / 4 + cp * 2 + 1];
      uint4 w;
      w.x = f2bf(v0.x) | (f2bf(v0.y) << 16);
      w.y = f2bf(v0.z) | (f2bf(v0.w) << 16);
      w.z = f2bf(v1.x) | (f2bf(v1.y) << 16);
      w.w = f2bf(v1.z) | (f2bf(v1.w) << 16);
      *(uint4*)&sp[row * LROW + cp * 8] = w;
    }
    // ---- stage A chunk transposed: thread owns 4 p-cols x 8 d's ----
    {
      float4 va[8];
#pragma unroll
      for (int i = 0; i < 8; ++i)
        va[i] = Ag[(size_t)(kc + dg * 8 + i) * (P_DIM / 4) + pg];
#pragma unroll
      for (int j = 0; j < 4; ++j) {
        float e0 = ((const float*)&va[0])[j], e1 = ((const float*)&va[1])[j];
        float e2 = ((const float*)&va[2])[j], e3 = ((const float*)&va[3])[j];
        float e4 = ((const float*)&va[4])[j], e5 = ((const float*)&va[5])[j];
        float e6 = ((const float*)&va[6])[j], e7 = ((const float*)&va[7])[j];
        nrm[j] = fmaf(e0, e0, nrm[j]); nrm[j] = fmaf(e1, e1, nrm[j]);
        nrm[j] = fmaf(e2, e2, nrm[j]); nrm[j] = fmaf(e3, e3, nrm[j]);
        nrm[j] = fmaf(e4, e4, nrm[j]); nrm[j] = fmaf(e5, e5, nrm[j]);
        nrm[j] = fmaf(e6, e6, nrm[j]); nrm[j] = fmaf(e7, e7, nrm[j]);
        uint4 w;
        w.x = f2bf(e0) | (f2bf(e1) << 16);
        w.y = f2bf(e2) | (f2bf(e3) << 16);
        w.z = f2bf(e4) | (f2bf(e5) << 16);
        w.w = f2bf(e6) | (f2bf(e7) << 16);
        *(uint4*)&sa[(pg * 4 + j) * LROW + dg * 8] = w;
      }
    }
    if (kc != 0) {                               // norms complete on last chunk
#pragma unroll
      for (int j = 0; j < 4; ++j) normred[dg * 64 + pg * 4 + j] = nrm[j];
    }
    __syncthreads();

    // ---- MFMA over this chunk: 8 k-steps ----
#pragma unroll
    for (int ks = 0; ks < 8; ++ks) {
      int k = ks * 16 + koff;
      bf16x8 af = *(const bf16x8*)&sp[mrow * LROW + k];
      bf16x8 bf = *(const bf16x8*)&sa[nrow * LROW + k];
      acc = __builtin_amdgcn_mfma_f32_32x32x16_bf16(af, bf, acc, 0, 0, 0);
    }
    __syncthreads();                             // frag reads done before restage/reuse
  }
  // acc reg r = x_unnorm[b = mt*32+(r&3)+8*(r>>2)+4*(lane>>5)][p = nt*32+(lane&31)]

  // ---- finish column norms -> invn[p] ----
  if (tid < 64) {
    float s = 0.f;
#pragma unroll
    for (int q = 0; q < 16; ++q) s += normred[q * 64 + tid];
    invn[tid] = rsqrtf(fmaxf(s, 1e-24f));        // 1/clamp_min(norm, 1e-12)
  }
  __syncthreads();
  const float invdt = invn[nt * 32 + (lane & 31)] * DT;

  // ---- Chebyshev trig: cos/sin sums over this lane's 16 b's, k = 1..16 ----
  float cs[NK - 1], ss[NK - 1];
#pragma unroll
  for (int k = 0; k < NK - 1; ++k) { cs[k] = 0.f; ss[k] = 0.f; }
#pragma unroll
  for (int r = 0; r < 16; ++r) {
    float th = acc[r] * invdt;
    float s1, c1;
    __sincosf(th, &s1, &c1);
    float twoc = 2.f * c1;
    float ckm1 = 1.f, skm1 = 0.f;
    float ck = c1, sk = s1;
    cs[0] += c1;
    ss[0] += s1;
#pragma unroll
    for (int k = 2; k < NK; ++k) {
      float cn = fmaf(twoc, ck, -ckm1);
      float sn = fmaf(twoc, sk, -skm1);
      cs[k - 1] += cn;
      ss[k - 1] += sn;
      ckm1 = ck; skm1 = sk; ck = cn; sk = sn;
    }
  }

  // ---- combine the two b-halves (lane L and L^32 share the same p col) ----
#pragma unroll
  for (int k = 0; k < NK - 1; ++k) {
    cs[k] += __shfl_xor(cs[k], 32, 64);
    ss[k] += __shfl_xor(ss[k], 32, 64);
  }

  // ---- planes (reuse tile LDS): cos[16][2 mt][64 p] @0, sin @2048 ----
  if (lane < 32) {
    int p = nt * 32 + (lane & 31);
#pragma unroll
    for (int k = 0; k < NK - 1; ++k) {
      smf[k * 128 + mt * 64 + p]        = cs[k];
      smf[2048 + k * 128 + mt * 64 + p] = ss[k];
    }
  }
  __syncthreads();

  // ---- per-(k,p) error + weight dot ----
  float part = 0.f;
#pragma unroll
  for (int r = 0; r < 4; ++r) {
    int e  = tid + r * 256;                      // 0..1023
    int k1 = e >> 6;
    int pl = e & 63;
    float C = smf[k1 * 128 + pl] + smf[k1 * 128 + 64 + pl];
    float S = smf[2048 + k1 * 128 + pl] + smf[2048 + k1 * 128 + 64 + pl];
    float cm  = C * (1.f / 64.f);
    float sm_ = S * (1.f / 64.f);
    float tk  = (float)(k1 + 1) * DT;
    float phi = __expf(-0.5f * tk * tk);
    float wk  = ((k1 == NK - 2) ? DT : 2.f * DT) * phi;   // k=16 endpoint
    float dc  = cm - phi;
    part = fmaf(wk, fmaf(dc, dc, sm_ * sm_), part);
  }
  part *= (1.f / 512.f);                         // * B / (T*P)

  // ---- block reduce -> one atomic per block ----
#pragma unroll
  for (int off = 32; off > 0; off >>= 1)
    part += __shfl_down(part, off, 64);
  __syncthreads();                               // done reading planes
  if (lane == 0) smf[4096 + wv] = part;          // 4096..4099 free (planes end at 4095)
  __syncthreads();
  if (tid == 0)
    atomicAdd(out, smf[4096] + smf[4097] + smf[4098] + smf[4099]);
}

// ---------------------------------------------------------------------------
extern "C" void kernel_launch(void* const* d_in, const int* in_sizes, int n_in,
                              void* d_out, int out_size, void* d_ws, size_t ws_size,
                              hipStream_t stream) {
  const float* proj = (const float*)d_in[0];     // (32,64,256) fp32
  const float* A    = (const float*)d_in[1];     // (256,1024) fp32
  float* out        = (float*)d_out;             // 1 fp32 scalar

  hipMemsetAsync(out, 0, sizeof(float), stream); // d_out poisoned each call
  sig_fused_kernel<<<dim3(16, 32), dim3(256), 0, stream>>>(proj, A, out);
}